// Round 6
// baseline (176.096 us; speedup 1.0000x reference)
//
#include <hip/hip_runtime.h>

constexpr int IN_F   = 32;
constexpr int OUT_F  = 128;
constexpr int BLOCK  = 256;
constexpr int WAVES  = BLOCK / 64;
constexpr int RSTAGE = 8;          // rows staged per wave per stage

using f32x2 = __attribute__((ext_vector_type(2))) float;

// Exchange lanes [0,32) <-> [32,64) between two registers (VALU, no LDS pipe).
// After: a = {a.row0, b.row0}, b = {a.row1, b.row1}  (row = 32-lane half)
__device__ __forceinline__ void swap32(float& a, float& b) {
    asm volatile("v_permlane32_swap_b32 %0, %1" : "+v"(a), "+v"(b));
}

__global__ __launch_bounds__(BLOCK, 4)
void rbf_kernel(const float* __restrict__ x,
                const float* __restrict__ centres,
                const float* __restrict__ log_sigmas,
                float* __restrict__ out,
                int rows_per_wave)
{
    __shared__ float4 xs[WAVES][2][RSTAGE][IN_F / 4];   // 8 KB total

    const int tid  = threadIdx.x;
    const int wv   = tid >> 6;
    const int lane = tid & 63;
    const int j    = lane & 31;
    const int h    = lane >> 5;        // which k-half this lane reads

    // ---- 4 half-centres: outputs 4j..4j+3, k in [16h, 16h+16) ----
    f32x2 ch[4][8];
    float q2[4];
    #pragma unroll
    for (int oo = 0; oo < 4; ++oo) {
        const float* cp = centres + (size_t)(4 * j + oo) * IN_F + 16 * h;
        float acc = 0.f;
        #pragma unroll
        for (int u = 0; u < 4; ++u) {
            const float4 c4 = *reinterpret_cast<const float4*>(cp + 4 * u);
            ch[oo][2*u+0] = (f32x2){c4.x, c4.y};
            ch[oo][2*u+1] = (f32x2){c4.z, c4.w};
            acc = fmaf(c4.x, c4.x, acc); acc = fmaf(c4.y, c4.y, acc);
            acc = fmaf(c4.z, c4.z, acc); acc = fmaf(c4.w, c4.w, acc);
        }
        q2[oo] = acc;
    }
    // full ||c||^2 for the two outputs this lane finalizes
    float a0 = q2[0], a1 = q2[1], a2 = q2[2], a3 = q2[3];
    swap32(a2, a0); const float c2f0 = a2 + a0;   // row0: c2[4j+2], row1: c2[4j]
    swap32(a3, a1); const float c2f1 = a3 + a1;   // row0: c2[4j+3], row1: c2[4j+1]
    const int o_fin = 4 * j + 2 * (h ^ 1);        // first output this lane stores
    const float iv0 = __expf(-2.0f * log_sigmas[o_fin]);
    const float iv1 = __expf(-2.0f * log_sigmas[o_fin + 1]);

    const size_t waveRow0 = ((size_t)blockIdx.x * WAVES + wv) * (size_t)rows_per_wave;
    const float* xb = x   + waveRow0 * IN_F;
    float*       ob = out + waveRow0 * OUT_F + o_fin;

    const int lr = lane >> 3;          // staging: row this lane loads
    const int lq = lane & 7;           // staging: float4 slot

    // ---- prologue: load stage 0 and stage 1 (loads issued before ds_write,
    //      so the write's vmcnt wait only covers v0) ----
    float4 v0 = *reinterpret_cast<const float4*>(xb + lr * IN_F + lq * 4);
    float4 vn = *reinterpret_cast<const float4*>(xb + (RSTAGE + lr) * IN_F + lq * 4);
    xs[wv][0][lr][lq] = v0;

    for (int it = 0; it < rows_per_wave; it += RSTAGE) {
        const int buf = (it >> 3) & 1;
        // stage t+1 into the other buffer; issue stage t+2 load (in flight under compute)
        if (it + RSTAGE < rows_per_wave) {
            xs[wv][buf ^ 1][lr][lq] = vn;
            if (it + 2 * RSTAGE < rows_per_wave)
                vn = *reinterpret_cast<const float4*>(
                    xb + (size_t)(it + 2 * RSTAGE + lr) * IN_F + lq * 4);
        }

        #pragma unroll
        for (int rr = 0; rr < RSTAGE; ++rr) {
            f32x2 p0 = {0.f,0.f}, p1 = {0.f,0.f}, p2 = {0.f,0.f}, p3 = {0.f,0.f};
            f32x2 px = {0.f,0.f};
            #pragma unroll
            for (int u = 0; u < 4; ++u) {
                // half-row read: lanes 0-31 one addr, lanes 32-63 addr+64B -> 0 conflicts
                const float4 xq = xs[wv][buf][rr][h * 4 + u];
                const f32x2 e0 = {xq.x, xq.y};
                const f32x2 e1 = {xq.z, xq.w};
                p0 = __builtin_elementwise_fma(e0, ch[0][2*u+0], p0);
                p0 = __builtin_elementwise_fma(e1, ch[0][2*u+1], p0);
                p1 = __builtin_elementwise_fma(e0, ch[1][2*u+0], p1);
                p1 = __builtin_elementwise_fma(e1, ch[1][2*u+1], p1);
                p2 = __builtin_elementwise_fma(e0, ch[2][2*u+0], p2);
                p2 = __builtin_elementwise_fma(e1, ch[2][2*u+1], p2);
                p3 = __builtin_elementwise_fma(e0, ch[3][2*u+0], p3);
                p3 = __builtin_elementwise_fma(e1, ch[3][2*u+1], p3);
                px = __builtin_elementwise_fma(e0, e0, px);
                px = __builtin_elementwise_fma(e1, e1, px);
            }
            float s0 = p0.x + p0.y, s1 = p1.x + p1.y;
            float s2 = p2.x + p2.y, s3 = p3.x + p3.y;
            float sxa = px.x + px.y, sxb = sxa;
            swap32(s2, s0);            // row0 lanes: both halves of out 4j+2; row1: out 4j
            swap32(s3, s1);            // row0: out 4j+3; row1: out 4j+1
            swap32(sxa, sxb);          // both halves of ||x||^2 everywhere
            const float x2 = sxa + sxb;
            const float d0 = s2 + s0;
            const float d1 = s3 + s1;
            const float t0 = fmaxf(fmaf(-2.0f, d0, x2 + c2f0), 0.0f);
            const float t1 = fmaxf(fmaf(-2.0f, d1, x2 + c2f1), 0.0f);
            f32x2 o;
            o.x = __expf(-t0 * iv0);
            o.y = __expf(-t1 * iv1);
            // per row: 64 lanes cover bytes [0,512) contiguously
            __builtin_nontemporal_store(o,
                reinterpret_cast<f32x2*>(ob + (size_t)(it + rr) * OUT_F));
        }
    }
}

extern "C" void kernel_launch(void* const* d_in, const int* in_sizes, int n_in,
                              void* d_out, int out_size, void* d_ws, size_t ws_size,
                              hipStream_t stream) {
    const float* x          = (const float*)d_in[0];
    const float* centres    = (const float*)d_in[1];
    const float* log_sigmas = (const float*)d_in[2];
    float* out = (float*)d_out;

    const int n = in_sizes[0] / IN_F;                   // 1,048,576 rows
    const int blocks = 4096;
    const int rows_per_wave = n / (blocks * WAVES);     // 64 (8 stages of 8)
    rbf_kernel<<<blocks, BLOCK, 0, stream>>>(x, centres, log_sigmas, out, rows_per_wave);
}

// Round 7
// 152.709 us; speedup vs baseline: 1.1531x; 1.1531x over previous
//
#include <hip/hip_runtime.h>

constexpr int IN_F   = 32;
constexpr int OUT_F  = 128;
constexpr int BLOCK  = 256;
constexpr int WAVES  = BLOCK / 64;
constexpr int RSTAGE = 8;          // rows staged per wave per iteration

using f32x2  = __attribute__((ext_vector_type(2)))  float;
using f32x16 = __attribute__((ext_vector_type(16))) float;

__global__ __launch_bounds__(BLOCK, 4)
void rbf_kernel(const float* __restrict__ x,
                const float* __restrict__ centres,
                const float* __restrict__ log_sigmas,
                float* __restrict__ out,
                int rows_per_wave)
{
    __shared__ float4 xs[WAVES][RSTAGE][IN_F / 4];
    __shared__ float  x2s[WAVES][RSTAGE];

    const int tid  = threadIdx.x;
    const int wv   = tid >> 6;
    const int lane = tid & 63;

    // ---- centres for outputs 2*lane, 2*lane+1 as NAMED f32x16 values ----
    // (whole-vector SSA values stay register-resident; arrays get demoted)
    const int o0 = lane * 2;
    const f32x16 c0lo = *reinterpret_cast<const f32x16*>(centres + (size_t)(o0 + 0) * IN_F);
    const f32x16 c0hi = *reinterpret_cast<const f32x16*>(centres + (size_t)(o0 + 0) * IN_F + 16);
    const f32x16 c1lo = *reinterpret_cast<const f32x16*>(centres + (size_t)(o0 + 1) * IN_F);
    const f32x16 c1hi = *reinterpret_cast<const f32x16*>(centres + (size_t)(o0 + 1) * IN_F + 16);

    float c2a = 0.f, c2b = 0.f;
    #pragma unroll
    for (int k = 0; k < 16; ++k) {
        c2a = fmaf(c0lo[k], c0lo[k], c2a);
        c2a = fmaf(c0hi[k], c0hi[k], c2a);
        c2b = fmaf(c1lo[k], c1lo[k], c2b);
        c2b = fmaf(c1hi[k], c1hi[k], c2b);
    }
    const float iv0 = __expf(-2.0f * log_sigmas[o0 + 0]);
    const float iv1 = __expf(-2.0f * log_sigmas[o0 + 1]);

    const size_t waveRow0 = ((size_t)blockIdx.x * WAVES + wv) * (size_t)rows_per_wave;
    const int rs = lane >> 3;      // staging: row this lane loads
    const int q  = lane & 7;       // staging: float4 slot

    for (int it = 0; it < rows_per_wave; it += RSTAGE) {
        // ---- stage 8 rows: one coalesced 1 KB load per wave ----
        const float4 v = *reinterpret_cast<const float4*>(
            x + (waveRow0 + it) * IN_F + lane * 4);
        float s;
        s = v.x * v.x;
        s = fmaf(v.y, v.y, s);
        s = fmaf(v.z, v.z, s);
        s = fmaf(v.w, v.w, s);
        s += __shfl_xor(s, 1);
        s += __shfl_xor(s, 2);
        s += __shfl_xor(s, 4);     // lanes sharing rs now hold full ||x||^2
        xs[wv][rs][q] = v;
        if (q == 0) x2s[wv][rs] = s;
        __syncthreads();

        #pragma unroll
        for (int rr = 0; rr < RSTAGE; ++rr) {
            float acc0 = 0.f, acc1 = 0.f;
            #pragma unroll
            for (int u = 0; u < 4; ++u) {
                const float4 xq = xs[wv][rr][u];          // wave-uniform: broadcast
                acc0 = fmaf(xq.x, c0lo[4*u+0], acc0);
                acc0 = fmaf(xq.y, c0lo[4*u+1], acc0);
                acc0 = fmaf(xq.z, c0lo[4*u+2], acc0);
                acc0 = fmaf(xq.w, c0lo[4*u+3], acc0);
                acc1 = fmaf(xq.x, c1lo[4*u+0], acc1);
                acc1 = fmaf(xq.y, c1lo[4*u+1], acc1);
                acc1 = fmaf(xq.z, c1lo[4*u+2], acc1);
                acc1 = fmaf(xq.w, c1lo[4*u+3], acc1);
            }
            #pragma unroll
            for (int u = 0; u < 4; ++u) {
                const float4 xq = xs[wv][rr][4 + u];
                acc0 = fmaf(xq.x, c0hi[4*u+0], acc0);
                acc0 = fmaf(xq.y, c0hi[4*u+1], acc0);
                acc0 = fmaf(xq.z, c0hi[4*u+2], acc0);
                acc0 = fmaf(xq.w, c0hi[4*u+3], acc0);
                acc1 = fmaf(xq.x, c1hi[4*u+0], acc1);
                acc1 = fmaf(xq.y, c1hi[4*u+1], acc1);
                acc1 = fmaf(xq.z, c1hi[4*u+2], acc1);
                acc1 = fmaf(xq.w, c1hi[4*u+3], acc1);
            }
            const float x2 = x2s[wv][rr];
            const float t0 = fmaxf(fmaf(-2.0f, acc0, x2 + c2a), 0.0f);
            const float t1 = fmaxf(fmaf(-2.0f, acc1, x2 + c2b), 0.0f);
            f32x2 o;
            o.x = __expf(-t0 * iv0);
            o.y = __expf(-t1 * iv1);
            // lane l writes bytes [8l, 8l+8): 512 B contiguous per wave per row
            __builtin_nontemporal_store(o,
                reinterpret_cast<f32x2*>(out + (waveRow0 + it + rr) * OUT_F + o0));
        }
        __syncthreads();           // protect xs before next stage overwrites
    }
}

extern "C" void kernel_launch(void* const* d_in, const int* in_sizes, int n_in,
                              void* d_out, int out_size, void* d_ws, size_t ws_size,
                              hipStream_t stream) {
    const float* x          = (const float*)d_in[0];
    const float* centres    = (const float*)d_in[1];
    const float* log_sigmas = (const float*)d_in[2];
    float* out = (float*)d_out;

    const int n = in_sizes[0] / IN_F;                   // 1,048,576 rows
    const int blocks = 2048;
    const int rows_per_block = n / blocks;              // 512
    const int rows_per_wave  = rows_per_block / WAVES;  // 128 (16 stages of 8)
    rbf_kernel<<<blocks, BLOCK, 0, stream>>>(x, centres, log_sigmas, out, rows_per_wave);
}